// Round 3
// baseline (514.362 us; speedup 1.0000x reference)
//
#include <hip/hip_runtime.h>

#define HIDDEN 5120
#define NEXP 160
#define NGRP 8
#define GSIZE 20
#define TOPKG 3
#define TOPK 6

#define KSP 2                    // K-split (partial planes)
#define BT 64                    // tokens per gemm block
#define KC 32                    // k per chunk (= one MFMA k-step)
#define NSTEP (HIDDEN / 32)      // 160 global k-steps
#define KPB (HIDDEN / KSP)       // 2560 k per block
#define NCH (KPB / KC)           // 80 chunks per block
#define CHU 1280                 // f16x8 units per packed-B chunk (640 hi + 640 lo)
#define F16_MIN_NORM 6.104e-5f   // denorm guard: MFMA may flush f16 denorms

typedef _Float16 f16;
typedef _Float16 f16x8 __attribute__((ext_vector_type(8)));
typedef float f32x4 __attribute__((ext_vector_type(4)));

__device__ __forceinline__ void gl_lds16(const void* g, void* l) {
    __builtin_amdgcn_global_load_lds((const __attribute__((address_space(1))) void*)g,
                                     (__attribute__((address_space(3))) void*)l, 16, 0, 0);
}

// ---------- K0: pack W fp32 -> chunk-contiguous f16 hi/lo in MFMA B-frag order ----
// chunk s (k-step of 32): unit u<640: hi, f=u/64, lane=u%64 -> w[f*16+(l&15)][s*32+(l>>4)*8+j]
//                         unit 640+u: matching lo = (w - f16(w)) * 4096
__global__ __launch_bounds__(256) void pack_w(const float* __restrict__ w,
                                              f16* __restrict__ bpk) {
    int idx = blockIdx.x * 256 + threadIdx.x;
    if (idx >= NSTEP * 10 * 64) return;
    int l = idx & 63;
    int rest = idx >> 6;
    int f = rest % 10;
    int s = rest / 10;
    int n = f * 16 + (l & 15);
    int k0 = s * 32 + (l >> 4) * 8;
    const float* src = w + (size_t)n * HIDDEN + k0;
    f16x8 hi, lo;
#pragma unroll
    for (int j = 0; j < 8; ++j) {
        float v = src[j];
        f16 hv = (fabsf(v) < F16_MIN_NORM) ? (f16)0.f : (f16)v;
        hi[j] = hv;
        lo[j] = (f16)((v - (float)hv) * 4096.0f);
    }
    f16x8* dst = (f16x8*)bpk;
    dst[(size_t)s * CHU + f * 64 + l] = hi;
    dst[(size_t)s * CHU + 640 + f * 64 + l] = lo;
}

// ---------- K1: split-f16 MFMA GEMM, partials [KSP][T][160] f32 ----------
// 4 waves/block (256 thr); wave = (tgg, eh) owns 32 tokens (2 M-frags) x 80 experts
// (5 N-frags): B frags read once per chunk, reused across both M-frags -> LDS reads
// 56 KB/chunk/block (was 96). LDS 56 KB -> 2 blocks/CU. All LDS access lane-linear.
__global__ __launch_bounds__(256, 2) void gemm_mfma(const float* __restrict__ x,
                                                    const f16* __restrict__ bpk,
                                                    float* __restrict__ part, int T) {
    __shared__ __align__(16) f16 Alds[2][512 * 8];   // 8 KB/buf: units 0..255 hi, 256..511 lo
    __shared__ __align__(16) f16 Blds[2][CHU * 8];   // 20 KB/buf

    const int tid  = threadIdx.x;
    const int lane = tid & 63;
    const int wv   = tid >> 6;        // 0..3
    const int tile = blockIdx.x >> 1;
    const int ks   = blockIdx.x & 1;
    const int t0   = tile * BT;
    const int tgg  = wv >> 1;         // token pair-group: M-frags {2tgg, 2tgg+1}
    const int eh   = wv & 1;          // expert half

    // A staging: thread tid owns unit tid = (mf=tid>>6, lane=tid&63):
    // token t0 + (tid>>6)*16 + (tid&15), k-octet ((tid>>4)&3) of the chunk
    const int arow = (tid >> 6) * 16 + (tid & 15);
    const int aq   = (tid >> 4) & 3;
    const float* xbase = x + (size_t)(t0 + arow) * HIDDEN + (size_t)ks * KPB + aq * 8;

    const f16x8* bpk8 = (const f16x8*)bpk + (size_t)(ks * NCH) * CHU;

    auto stageB = [&](int b, int c) {
        const f16x8* src = bpk8 + (size_t)c * CHU + wv * 320 + lane;
#pragma unroll
        for (int r = 0; r < 5; ++r)
            gl_lds16(src + r * 64, &Blds[b][(wv * 320 + r * 64) * 8]);
    };

    auto cvtA = [&](int b, f32x4 v0, f32x4 v1) {
        f16x8 hi, lo;
#pragma unroll
        for (int j = 0; j < 8; ++j) {
            float vv = (j < 4) ? v0[j] : v1[j - 4];
            f16 hv = (fabsf(vv) < F16_MIN_NORM) ? (f16)0.f : (f16)vv;
            hi[j] = hv;
            lo[j] = (f16)((vv - (float)hv) * 4096.0f);
        }
        *(f16x8*)&Alds[b][tid * 8] = hi;              // lane-linear ds_write_b128
        *(f16x8*)&Alds[b][(256 + tid) * 8] = lo;
    };

    f32x4 acc0[2][5], acc1[2][5];
    const f32x4 z4 = {0.f, 0.f, 0.f, 0.f};
#pragma unroll
    for (int m = 0; m < 2; ++m)
#pragma unroll
        for (int nf = 0; nf < 5; ++nf) { acc0[m][nf] = z4; acc1[m][nf] = z4; }

    // prologue: chunk 0 -> buf 0
    stageB(0, 0);
    f32x4 xv0 = __builtin_nontemporal_load((const f32x4*)xbase);
    f32x4 xv1 = __builtin_nontemporal_load((const f32x4*)(xbase + 4));
    cvtA(0, xv0, xv1);
    __syncthreads();

    int buf = 0;
    for (int c = 0; c < NCH; ++c) {
        if (c + 1 < NCH) {            // issue next-chunk loads first (latency hiding)
            stageB(buf ^ 1, c + 1);
            xv0 = __builtin_nontemporal_load((const f32x4*)(xbase + (size_t)(c + 1) * KC));
            xv1 = __builtin_nontemporal_load((const f32x4*)(xbase + (size_t)(c + 1) * KC + 4));
        }

        const f16* Ab = Alds[buf];
        const f16* Bb = Blds[buf];
        f16x8 ah[2], al[2];
#pragma unroll
        for (int m = 0; m < 2; ++m) {
            ah[m] = *(const f16x8*)&Ab[((tgg * 2 + m) * 64 + lane) * 8];
            al[m] = *(const f16x8*)&Ab[((256 + (tgg * 2 + m) * 64) + lane) * 8];
        }
#pragma unroll
        for (int nf = 0; nf < 5; ++nf) {
            f16x8 bh = *(const f16x8*)&Bb[((eh * 5 + nf) * 64 + lane) * 8];
            f16x8 bl = *(const f16x8*)&Bb[((640 + (eh * 5 + nf) * 64) + lane) * 8];
#pragma unroll
            for (int m = 0; m < 2; ++m) {
                acc0[m][nf] = __builtin_amdgcn_mfma_f32_16x16x32_f16(ah[m], bh, acc0[m][nf], 0, 0, 0);
                acc1[m][nf] = __builtin_amdgcn_mfma_f32_16x16x32_f16(ah[m], bl, acc1[m][nf], 0, 0, 0);
                acc1[m][nf] = __builtin_amdgcn_mfma_f32_16x16x32_f16(al[m], bh, acc1[m][nf], 0, 0, 0);
            }
        }

        if (c + 1 < NCH) cvtA(buf ^ 1, xv0, xv1);
        __syncthreads();
        buf ^= 1;
    }

    // epilogue: logit = acc0 + acc1/4096; C/D: col=lane&15 (expert), row=(lane>>4)*4+r
    const int m16 = lane & 15, h4 = lane >> 4;
    const float s12 = 1.0f / 4096.0f;
#pragma unroll
    for (int m = 0; m < 2; ++m)
#pragma unroll
        for (int nf = 0; nf < 5; ++nf) {
            int e  = eh * 80 + nf * 16 + m16;
            int tb = t0 + (tgg * 2 + m) * 16 + h4 * 4;
#pragma unroll
            for (int r = 0; r < 4; ++r)
                part[((size_t)ks * T + tb + r) * NEXP + e] = acc0[m][nf][r] + acc1[m][nf][r] * s12;
        }
}

// ---------- K2: 8 lanes per token: combine partials + grouped top-k ----------
__global__ __launch_bounds__(512) void moe_topk3(const float* __restrict__ part,
                                                 float* __restrict__ out, int T) {
    const int tid = threadIdx.x;
    const int tl  = tid >> 3;
    const int g   = tid & 7;
    const int t   = blockIdx.x * 64 + tl;

    const float* r0 = part + (size_t)t * NEXP + g * GSIZE;
    const float* r1 = r0 + (size_t)T * NEXP;

    float v[GSIZE];
    float gmx = -3e38f;
#pragma unroll
    for (int j = 0; j < 5; ++j) {
        f32x4 a = *(const f32x4*)(r0 + j * 4);
        f32x4 b = *(const f32x4*)(r1 + j * 4);
#pragma unroll
        for (int cc = 0; cc < 4; ++cc) {
            float s = a[cc] + b[cc];
            v[j * 4 + cc] = s;
            gmx = fmaxf(gmx, s);
        }
    }

    float gm[NGRP];
#pragma unroll
    for (int i = 0; i < NGRP; ++i) gm[i] = __shfl(gmx, i, 8);

    // top-3 groups, lowest index wins ties (matches stable lax.top_k)
    unsigned gmask = 0;
#pragma unroll
    for (int r = 0; r < TOPKG; ++r) {
        float bv = -3e38f; int bi = 0;
#pragma unroll
        for (int gg = 0; gg < NGRP; ++gg) {
            bool elig = !((gmask >> gg) & 1);
            if (elig && gm[gg] > bv) { bv = gm[gg]; bi = gg; }
        }
        gmask |= 1u << bi;
    }
    const bool sel = (gmask >> g) & 1;

    // local stable top-6 of my group (value desc, index asc)
    float lv[TOPK]; int li[TOPK];
#pragma unroll
    for (int r = 0; r < TOPK; ++r) { lv[r] = -3e38f; li[r] = 1 << 20; }
    if (sel) {
#pragma unroll
        for (int j = 0; j < GSIZE; ++j) {
            float sv = v[j];
            int e = g * GSIZE + j;
            if (sv > lv[TOPK - 1]) {
                lv[TOPK - 1] = sv; li[TOPK - 1] = e;
#pragma unroll
                for (int q = TOPK - 1; q > 0; --q) {
                    if (lv[q] > lv[q - 1]) {
                        float tv = lv[q]; lv[q] = lv[q - 1]; lv[q - 1] = tv;
                        int ti = li[q]; li[q] = li[q - 1]; li[q - 1] = ti;
                    }
                }
            }
        }
    }

    // 8-way merge: butterfly argmax of list heads (tie -> lower e), winner pops
    float vals[TOPK]; int idxs[TOPK];
#pragma unroll
    for (int r = 0; r < TOPK; ++r) {
        float cv = lv[0]; int ce = li[0];
        float bv = cv; int be = ce;
#pragma unroll
        for (int m = 1; m < 8; m <<= 1) {
            float ov = __shfl_xor(bv, m, 8);
            int   oe = __shfl_xor(be, m, 8);
            if (ov > bv || (ov == bv && oe < be)) { bv = ov; be = oe; }
        }
        vals[r] = bv; idxs[r] = be;
        if (be == ce) {
#pragma unroll
            for (int q = 0; q < TOPK - 1; ++q) { lv[q] = lv[q + 1]; li[q] = li[q + 1]; }
            lv[TOPK - 1] = -3e38f; li[TOPK - 1] = 1 << 20;
        }
    }

    if (g == 0) {
        float m0 = vals[0], ssum = 0.f, w6[TOPK];
#pragma unroll
        for (int r = 0; r < TOPK; ++r) { w6[r] = expf(vals[r] - m0); ssum += w6[r]; }
        float inv = 1.f / (ssum + 1e-20f);
#pragma unroll
        for (int r = 0; r < TOPK; ++r) {
            out[(size_t)t * TOPK + r] = (float)idxs[r];
            out[(size_t)T * TOPK + (size_t)t * TOPK + r] = w6[r] * inv;
        }
    }
}

extern "C" void kernel_launch(void* const* d_in, const int* in_sizes, int n_in,
                              void* d_out, int out_size, void* d_ws, size_t ws_size,
                              hipStream_t stream) {
    const float* x = (const float*)d_in[0];
    const float* w = (const float*)d_in[1];
    float* out = (float*)d_out;
    const int T = in_sizes[0] / HIDDEN;  // 16384

    f16* bpk    = (f16*)d_ws;                              // 3.28 MB packed B
    float* part = (float*)d_ws + (size_t)HIDDEN * NEXP;    // KSP * T * 160 f32 (21 MB)

    pack_w<<<(NSTEP * 10 * 64 + 255) / 256, 256, 0, stream>>>(w, bpk);
    gemm_mfma<<<(T / BT) * KSP, 256, 0, stream>>>(x, bpk, part, T);
    moe_topk3<<<T / 64, 512, 0, stream>>>(part, out, T);
}

// Round 6
// 498.989 us; speedup vs baseline: 1.0308x; 1.0308x over previous
//
#include <hip/hip_runtime.h>

#define HIDDEN 5120
#define NEXP 160
#define NGRP 8
#define GSIZE 20
#define TOPKG 3
#define TOPK 6

#define BT 256                   // tokens per gemm block (8 waves x 32)
#define KC 32                    // k per chunk (= one MFMA k-step)
#define NSTEP (HIDDEN / 32)      // 160 global k-steps
#define CHU 1280                 // f16x8 units per packed-B chunk (640 hi + 640 lo)
#define F16_MIN_NORM 6.104e-5f   // denorm guard: MFMA may flush f16 denorms

typedef _Float16 f16;
typedef _Float16 f16x8 __attribute__((ext_vector_type(8)));
typedef float f32x4 __attribute__((ext_vector_type(4)));

__device__ __forceinline__ void gl_lds16(const void* g, void* l) {
    __builtin_amdgcn_global_load_lds((const __attribute__((address_space(1))) void*)g,
                                     (__attribute__((address_space(3))) void*)l, 16, 0, 0);
}

// ---------- K0: pack W fp32 -> chunk-contiguous f16 hi/lo in MFMA B-frag order ----
// chunk s (k-step of 32): unit u<640: hi, f=u/64, lane=u%64 -> w[f*16+(l&15)][s*32+(l>>4)*8+j]
//                         unit 640+u: matching lo = (w - f16(w)) * 4096
__global__ __launch_bounds__(256) void pack_w(const float* __restrict__ w,
                                              f16* __restrict__ bpk) {
    int idx = blockIdx.x * 256 + threadIdx.x;
    if (idx >= NSTEP * 10 * 64) return;
    int l = idx & 63;
    int rest = idx >> 6;
    int f = rest % 10;
    int s = rest / 10;
    int n = f * 16 + (l & 15);
    int k0 = s * 32 + (l >> 4) * 8;
    const float* src = w + (size_t)n * HIDDEN + k0;
    f16x8 hi, lo;
#pragma unroll
    for (int j = 0; j < 8; ++j) {
        float v = src[j];
        f16 hv = (fabsf(v) < F16_MIN_NORM) ? (f16)0.f : (f16)v;
        hi[j] = hv;
        lo[j] = (f16)((v - (float)hv) * 4096.0f);
    }
    f16x8* dst = (f16x8*)bpk;
    dst[(size_t)s * CHU + f * 64 + l] = hi;
    dst[(size_t)s * CHU + 640 + f * 64 + l] = lo;
}

// ---------- K1: split-f16 MFMA GEMM, partials [KSP][T][160] f32 ----------
// 8 waves/block; wave = 32 tokens (2 M-frags) x 160 experts (10 N-frags).
// A: lane-owned, loaded f32 direct from global (nontemporal), hi/lo f16 in-register
//    -> x read exactly once, zero A-LDS traffic.
// B: 20 KB/chunk staged to LDS via global_load_lds (waves 0..4, 4 contiguous units
//    each), double-buffered; each frag read once per wave per chunk, reused across
//    both M-frags.
// Per-CU per-chunk: HBM 32 KB (~3100 cy, binding) > MFMA 2300 > LDS 2100.
template <int KSP>
__global__ __launch_bounds__(512, 2) void gemm_mfma(const float* __restrict__ x,
                                                    const f16* __restrict__ bpk,
                                                    float* __restrict__ part, int T) {
    constexpr int KPB = HIDDEN / KSP;   // k per block
    constexpr int NCH = KPB / KC;       // chunks per block
    __shared__ __align__(16) f16 Blds[2][CHU * 8];   // 20 KB per buf

    const int tid  = threadIdx.x;
    const int lane = tid & 63;
    const int wv   = tid >> 6;                  // 0..7
    const int tile = blockIdx.x / KSP;
    const int ks   = blockIdx.x % KSP;
    const int t0   = tile * BT;
    const int m16  = lane & 15, h4 = lane >> 4;

    // this lane's two A rows (M-frags m=0,1), k-octet h4
    const float* xr0 = x + (size_t)(t0 + wv * 32 + m16) * HIDDEN + (size_t)ks * KPB + h4 * 8;
    const float* xr1 = xr0 + (size_t)16 * HIDDEN;

    const f16x8* bpk8 = (const f16x8*)bpk + (size_t)(ks * NCH) * CHU;

    auto stageB = [&](int b, int c) {
        if (wv < 5) {                           // wave-uniform: waves 0..4 x 4 units = 20
            const f16x8* src = bpk8 + (size_t)c * CHU + wv * 256 + lane;
            f16* dst = Blds[b] + (size_t)wv * 256 * 8;
#pragma unroll
            for (int i = 0; i < 4; ++i)
                gl_lds16(src + i * 64, dst + (size_t)i * 64 * 8);
        }
    };

    auto cvt8 = [&](f32x4 a, f32x4 b, f16x8& hi, f16x8& lo) {
#pragma unroll
        for (int j = 0; j < 8; ++j) {
            float v = (j < 4) ? a[j] : b[j - 4];
            f16 hv = (fabsf(v) < F16_MIN_NORM) ? (f16)0.f : (f16)v;
            hi[j] = hv;
            lo[j] = (f16)((v - (float)hv) * 4096.0f);
        }
    };

    f32x4 acc0[2][10], acc1[2][10];
    const f32x4 z4 = {0.f, 0.f, 0.f, 0.f};
#pragma unroll
    for (int m = 0; m < 2; ++m)
#pragma unroll
        for (int nf = 0; nf < 10; ++nf) { acc0[m][nf] = z4; acc1[m][nf] = z4; }

    // prologue: B chunk 0 -> buf 0; A chunk 0 -> registers
    stageB(0, 0);
    f32x4 p00 = __builtin_nontemporal_load((const f32x4*)xr0);
    f32x4 p01 = __builtin_nontemporal_load((const f32x4*)(xr0 + 4));
    f32x4 p10 = __builtin_nontemporal_load((const f32x4*)xr1);
    f32x4 p11 = __builtin_nontemporal_load((const f32x4*)(xr1 + 4));
    f16x8 ah[2], al[2];
    cvt8(p00, p01, ah[0], al[0]);
    cvt8(p10, p11, ah[1], al[1]);
    __syncthreads();

    int buf = 0;
    for (int c = 0; c < NCH; ++c) {
        if (c + 1 < NCH) {                      // issue next-chunk loads first
            stageB(buf ^ 1, c + 1);
            const float* n0 = xr0 + (size_t)(c + 1) * KC;
            const float* n1 = xr1 + (size_t)(c + 1) * KC;
            p00 = __builtin_nontemporal_load((const f32x4*)n0);
            p01 = __builtin_nontemporal_load((const f32x4*)(n0 + 4));
            p10 = __builtin_nontemporal_load((const f32x4*)n1);
            p11 = __builtin_nontemporal_load((const f32x4*)(n1 + 4));
        }

        const f16* Bb = Blds[buf];
#pragma unroll
        for (int nf = 0; nf < 10; ++nf) {
            f16x8 bh = *(const f16x8*)&Bb[(nf * 64 + lane) * 8];
            f16x8 bl = *(const f16x8*)&Bb[((640 + nf * 64) + lane) * 8];
#pragma unroll
            for (int m = 0; m < 2; ++m) {
                acc0[m][nf] = __builtin_amdgcn_mfma_f32_16x16x32_f16(ah[m], bh, acc0[m][nf], 0, 0, 0);
                acc1[m][nf] = __builtin_amdgcn_mfma_f32_16x16x32_f16(ah[m], bl, acc1[m][nf], 0, 0, 0);
                acc1[m][nf] = __builtin_amdgcn_mfma_f32_16x16x32_f16(al[m], bh, acc1[m][nf], 0, 0, 0);
            }
        }

        if (c + 1 < NCH) {                      // convert next chunk after current use
            cvt8(p00, p01, ah[0], al[0]);
            cvt8(p10, p11, ah[1], al[1]);
        }
        __syncthreads();
        buf ^= 1;
    }

    // epilogue: logit = acc0 + acc1/4096; C/D: col=lane&15 (expert), row=h4*4+r (token)
    const float s12 = 1.0f / 4096.0f;
#pragma unroll
    for (int m = 0; m < 2; ++m) {
        int tb = t0 + wv * 32 + m * 16 + h4 * 4;
#pragma unroll
        for (int nf = 0; nf < 10; ++nf) {
            int e = nf * 16 + m16;
#pragma unroll
            for (int r = 0; r < 4; ++r)
                part[((size_t)ks * T + tb + r) * NEXP + e] = acc0[m][nf][r] + acc1[m][nf][r] * s12;
        }
    }
}

// ---------- K2: 8 lanes per token: combine partials + grouped top-k ----------
template <int KSP>
__global__ __launch_bounds__(512) void moe_topk3(const float* __restrict__ part,
                                                 float* __restrict__ out, int T) {
    const int tid = threadIdx.x;
    const int tl  = tid >> 3;
    const int g   = tid & 7;
    const int t   = blockIdx.x * 64 + tl;

    const float* r0 = part + (size_t)t * NEXP + g * GSIZE;
    const size_t plane = (size_t)T * NEXP;

    float v[GSIZE];
    float gmx = -3e38f;
#pragma unroll
    for (int j = 0; j < 5; ++j) {
        f32x4 s = *(const f32x4*)(r0 + j * 4);
#pragma unroll
        for (int p = 1; p < KSP; ++p) {
            f32x4 a = *(const f32x4*)(r0 + (size_t)p * plane + j * 4);
            s[0] += a[0]; s[1] += a[1]; s[2] += a[2]; s[3] += a[3];
        }
#pragma unroll
        for (int cc = 0; cc < 4; ++cc) {
            v[j * 4 + cc] = s[cc];
            gmx = fmaxf(gmx, s[cc]);
        }
    }

    float gm[NGRP];
#pragma unroll
    for (int i = 0; i < NGRP; ++i) gm[i] = __shfl(gmx, i, 8);

    // top-3 groups, lowest index wins ties (matches stable lax.top_k)
    unsigned gmask = 0;
#pragma unroll
    for (int r = 0; r < TOPKG; ++r) {
        float bv = -3e38f; int bi = 0;
#pragma unroll
        for (int gg = 0; gg < NGRP; ++gg) {
            bool elig = !((gmask >> gg) & 1);
            if (elig && gm[gg] > bv) { bv = gm[gg]; bi = gg; }
        }
        gmask |= 1u << bi;
    }
    const bool sel = (gmask >> g) & 1;

    // local stable top-6 of my group (value desc, index asc)
    float lv[TOPK]; int li[TOPK];
#pragma unroll
    for (int r = 0; r < TOPK; ++r) { lv[r] = -3e38f; li[r] = 1 << 20; }
    if (sel) {
#pragma unroll
        for (int j = 0; j < GSIZE; ++j) {
            float sv = v[j];
            int e = g * GSIZE + j;
            if (sv > lv[TOPK - 1]) {
                lv[TOPK - 1] = sv; li[TOPK - 1] = e;
#pragma unroll
                for (int q = TOPK - 1; q > 0; --q) {
                    if (lv[q] > lv[q - 1]) {
                        float tv = lv[q]; lv[q] = lv[q - 1]; lv[q - 1] = tv;
                        int ti = li[q]; li[q] = li[q - 1]; li[q - 1] = ti;
                    }
                }
            }
        }
    }

    // 8-way merge: butterfly argmax of list heads (tie -> lower e), winner pops
    float vals[TOPK]; int idxs[TOPK];
#pragma unroll
    for (int r = 0; r < TOPK; ++r) {
        float cv = lv[0]; int ce = li[0];
        float bv = cv; int be = ce;
#pragma unroll
        for (int m = 1; m < 8; m <<= 1) {
            float ov = __shfl_xor(bv, m, 8);
            int   oe = __shfl_xor(be, m, 8);
            if (ov > bv || (ov == bv && oe < be)) { bv = ov; be = oe; }
        }
        vals[r] = bv; idxs[r] = be;
        if (be == ce) {
#pragma unroll
            for (int q = 0; q < TOPK - 1; ++q) { lv[q] = lv[q + 1]; li[q] = li[q + 1]; }
            lv[TOPK - 1] = -3e38f; li[TOPK - 1] = 1 << 20;
        }
    }

    if (g == 0) {
        float m0 = vals[0], ssum = 0.f, w6[TOPK];
#pragma unroll
        for (int r = 0; r < TOPK; ++r) { w6[r] = expf(vals[r] - m0); ssum += w6[r]; }
        float inv = 1.f / (ssum + 1e-20f);
#pragma unroll
        for (int r = 0; r < TOPK; ++r) {
            out[(size_t)t * TOPK + r] = (float)idxs[r];
            out[(size_t)T * TOPK + (size_t)t * TOPK + r] = w6[r] * inv;
        }
    }
}

extern "C" void kernel_launch(void* const* d_in, const int* in_sizes, int n_in,
                              void* d_out, int out_size, void* d_ws, size_t ws_size,
                              hipStream_t stream) {
    const float* x = (const float*)d_in[0];
    const float* w = (const float*)d_in[1];
    float* out = (float*)d_out;
    const int T = in_sizes[0] / HIDDEN;  // 16384

    f16* bpk    = (f16*)d_ws;                              // 3.28 MB packed B (hi+lo)
    float* part = (float*)d_ws + (size_t)HIDDEN * NEXP;    // KSP * T * 160 f32

    pack_w<<<(NSTEP * 10 * 64 + 255) / 256, 256, 0, stream>>>(w, bpk);

    size_t need4 = ((size_t)HIDDEN * NEXP + (size_t)4 * T * NEXP) * sizeof(float);
    if (ws_size >= need4) {
        gemm_mfma<4><<<(T / BT) * 4, 512, 0, stream>>>(x, bpk, part, T);  // 256 blocks = 1/CU
        moe_topk3<4><<<T / 64, 512, 0, stream>>>(part, out, T);
    } else {
        gemm_mfma<2><<<(T / BT) * 2, 512, 0, stream>>>(x, bpk, part, T);
        moe_topk3<2><<<T / 64, 512, 0, stream>>>(part, out, T);
    }
}